// Round 3
// baseline (451.344 us; speedup 1.0000x reference)
//
#include <hip/hip_runtime.h>
#include <hip/hip_bf16.h>

// Encoding (deep-TEN) fused MFMA kernel for MI355X (gfx950), round 3.
// x:(B,C,H,W) fp32, codewords:(K,C) fp32, scale:(K) -> enc:(B,K,C) fp32
//
// prep kernel: cw fp32 -> bf16 in d_ws (+ c2[k]). Removes cw from LDS.
// main kernel: LDS 75.6 KB -> 2 blocks/CU (8 waves/CU) for latency hiding.
//   staging: float4-coalesced x loads, channel-pair pack, ds_write_b128.
//   matmul1 XC^T[k][n]: B-frags from x_cp LDS (4x ds_read_b32, bank-clean),
//     A-frags from global bf16 cw (L1/L2-hot). x2 exact fp32 via partials.
//   softmax in registers (C-layout, xor-shfl 16/32); aw -> aw_lds bf16.
//   matmul2 ENC[k][c]: A from aw_lds (b128), B from x_cp (2x b128 +
//     v_perm_b32 parity extract), 64 persistent fp32 acc/lane.
//   Epilogue: block awsum, fold -awsum*cw (fp32), atomicAdd into zeroed out.

typedef float  f32x4  __attribute__((ext_vector_type(4)));
typedef short  bf16x8 __attribute__((ext_vector_type(8)));

namespace {
constexpr int Cc   = 512;
constexpr int Nc   = 9216;   // 96*96
constexpr int Kc   = 32;
constexpr int XROW = 68;     // u32 per c-pair row (272 B): staging writes 2-way, reads clean
constexpr int SAH  = 72;     // aw_lds halfwords per row (144 B, 16B-aligned)
}

static __device__ inline unsigned short f2bf(float f) {
    unsigned int u = __float_as_uint(f);
    u += 0x7fffu + ((u >> 16) & 1u);      // RNE (finite inputs)
    return (unsigned short)(u >> 16);
}
static __device__ inline unsigned int pack_bf16(float a, float b) {
    return (unsigned int)f2bf(a) | ((unsigned int)f2bf(b) << 16);
}
static __device__ inline bf16x8 u4_frag(uint4 d) {
    union { uint4 u; bf16x8 v; } cv; cv.u = d; return cv.v;
}

// ---- prep: cw -> bf16 in ws, c2[k] ----
__global__ void enc_prep(const float* __restrict__ cw,
                         unsigned short* __restrict__ cwb,
                         float* __restrict__ c2)
{
    const int k = blockIdx.x;           // 32 blocks
    const int t = threadIdx.x;          // 256 threads
    float s = 0.f;
    #pragma unroll
    for (int h = 0; h < 2; ++h) {
        const int c = t + 256 * h;
        const float v = cw[k * Cc + c];
        cwb[k * Cc + c] = f2bf(v);
        s = fmaf(v, v, s);
    }
    s += __shfl_xor(s, 1);  s += __shfl_xor(s, 2);  s += __shfl_xor(s, 4);
    s += __shfl_xor(s, 8);  s += __shfl_xor(s, 16); s += __shfl_xor(s, 32);
    __shared__ float ps[4];
    if ((t & 63) == 0) ps[t >> 6] = s;
    __syncthreads();
    if (t == 0) c2[k] = ps[0] + ps[1] + ps[2] + ps[3];
}

__launch_bounds__(256, 2)
__global__ void enc_mfma2(const float* __restrict__ x,
                          const float* __restrict__ cw,
                          const float* __restrict__ scale,
                          const unsigned short* __restrict__ cwb,
                          const float* __restrict__ c2g,
                          float* __restrict__ out)
{
    __shared__ __attribute__((aligned(16))) unsigned int   x_cp[256 * XROW];  // 69632 B
    __shared__ __attribute__((aligned(16))) unsigned short aw_lds[Kc * SAH];  //  4608 B
    __shared__ __attribute__((aligned(16))) float x2p[4][64];                 //  1024 B
    __shared__ float sc_lds[Kc], c2_lds[Kc], awsum[Kc];

    const int tid  = threadIdx.x;
    const int wv   = tid >> 6;          // wave 0..3
    const int nloc = tid & 15;
    const int g    = (tid >> 4) & 3;
    const int i_q  = tid & 15;          // staging n-quad
    const int cp0  = tid >> 4;          // staging base c-pair 0..15

    const int b   = blockIdx.x >> 5;
    const int grp = blockIdx.x & 31;
    const int tstart = (grp < 16) ? grp * 5 : 80 + (grp - 16) * 4;
    const int tcnt   = (grp < 16) ? 5 : 4;
    const float* __restrict__ xb = x + (size_t)b * Cc * Nc;

    if (tid < Kc) { sc_lds[tid] = scale[tid]; c2_lds[tid] = c2g[tid]; awsum[tid] = 0.f; }
    __syncthreads();

    // per-lane k constants (MFMA C-layout rows: k = 16t + 4g + r)
    float sc8[8], c28[8];
    #pragma unroll
    for (int i = 0; i < 8; ++i) {
        const int k = 16 * (i >> 2) + 4 * g + (i & 3);
        sc8[i] = sc_lds[k];
        c28[i] = c2_lds[k];
    }

    f32x4 acc2[2][8];
    #pragma unroll
    for (int t = 0; t < 2; ++t)
        #pragma unroll
        for (int ct = 0; ct < 8; ++ct) acc2[t][ct] = (f32x4)0.f;
    float awacc[8] = {0.f,0.f,0.f,0.f,0.f,0.f,0.f,0.f};

    const unsigned psel = (nloc & 1) ? 0x07060302u : 0x05040100u;

    for (int tt = 0; tt < tcnt; ++tt) {
        const int n0 = (tstart + tt) * 64;
        __syncthreads();   // prev matmul2 x_cp/aw reads + prev softmax x2p reads done

        // ---- staging: 16 cells of (c-pair, n-quad); float4 loads, b128 writes ----
        float x2q[4] = {0.f, 0.f, 0.f, 0.f};
        #pragma unroll 8
        for (int j = 0; j < 16; ++j) {
            const int cp = cp0 + 16 * j;
            const float* pa = xb + (size_t)(2 * cp) * Nc + n0 + 4 * i_q;
            const float4 va = *(const float4*)pa;
            const float4 vb = *(const float4*)(pa + Nc);
            x2q[0] = fmaf(va.x, va.x, fmaf(vb.x, vb.x, x2q[0]));
            x2q[1] = fmaf(va.y, va.y, fmaf(vb.y, vb.y, x2q[1]));
            x2q[2] = fmaf(va.z, va.z, fmaf(vb.z, vb.z, x2q[2]));
            x2q[3] = fmaf(va.w, va.w, fmaf(vb.w, vb.w, x2q[3]));
            uint4 pk;
            pk.x = pack_bf16(va.x, vb.x);
            pk.y = pack_bf16(va.y, vb.y);
            pk.z = pack_bf16(va.z, vb.z);
            pk.w = pack_bf16(va.w, vb.w);
            *(uint4*)&x_cp[cp * XROW + 4 * i_q] = pk;
        }
        // x2 wave partials (over this wave's channel subset) -> x2p[wv][n]
        #pragma unroll
        for (int r = 0; r < 4; ++r) {
            x2q[r] += __shfl_xor(x2q[r], 16);
            x2q[r] += __shfl_xor(x2q[r], 32);
        }
        if ((tid & 63) < 16)
            *(float4*)&x2p[wv][4 * i_q] = make_float4(x2q[0], x2q[1], x2q[2], x2q[3]);
        __syncthreads();

        // ---- matmul1: XC^T[k][n], B from x_cp LDS, A from global bf16 cw ----
        f32x4 acc1[2];
        acc1[0] = (f32x4)0.f; acc1[1] = (f32x4)0.f;
        #pragma unroll 4
        for (int cs = 0; cs < 16; ++cs) {
            const int rb = (cs * 16 + g * 4) * XROW + 16 * wv + nloc;
            uint4 bf;
            bf.x = x_cp[rb];
            bf.y = x_cp[rb + XROW];
            bf.z = x_cp[rb + 2 * XROW];
            bf.w = x_cp[rb + 3 * XROW];
            const bf16x8 bfr = u4_frag(bf);
            #pragma unroll
            for (int t = 0; t < 2; ++t) {
                const uint4 af = *(const uint4*)&cwb[(16 * t + nloc) * Cc + cs * 32 + g * 8];
                acc1[t] = __builtin_amdgcn_mfma_f32_16x16x32_bf16(u4_frag(af), bfr, acc1[t], 0, 0, 0);
            }
        }

        // ---- softmax over K=32 in registers; n = 16*wv + nloc ----
        const int ncol = 16 * wv + nloc;
        const float x2 = x2p[0][ncol] + x2p[1][ncol] + x2p[2][ncol] + x2p[3][ncol];
        float l[8], aw[8];
        float m = -1e30f;
        #pragma unroll
        for (int i = 0; i < 8; ++i) {
            const float xc = acc1[i >> 2][i & 3];
            l[i] = sc8[i] * (x2 - 2.f * xc + c28[i]);
            m = fmaxf(m, l[i]);
        }
        m = fmaxf(m, __shfl_xor(m, 16));
        m = fmaxf(m, __shfl_xor(m, 32));
        float s = 0.f;
        #pragma unroll
        for (int i = 0; i < 8; ++i) { aw[i] = __expf(l[i] - m); s += aw[i]; }
        s += __shfl_xor(s, 16);
        s += __shfl_xor(s, 32);
        const float inv = 1.f / s;
        #pragma unroll
        for (int i = 0; i < 8; ++i) {
            aw[i] *= inv;
            awacc[i] += aw[i];
            const int k = 16 * (i >> 2) + 4 * g + (i & 3);
            aw_lds[k * SAH + ncol] = f2bf(aw[i]);
        }
        __syncthreads();

        // ---- matmul2: ENC[k][c] += AW^T · X^T over 64 n ----
        #pragma unroll
        for (int ns = 0; ns < 2; ++ns) {
            bf16x8 afr[2];
            #pragma unroll
            for (int t = 0; t < 2; ++t)
                afr[t] = u4_frag(*(const uint4*)&aw_lds[(16 * t + nloc) * SAH + ns * 32 + g * 8]);
            #pragma unroll
            for (int ct = 0; ct < 8; ++ct) {
                const int base = (64 * wv + 8 * ct + (nloc >> 1)) * XROW + ns * 32 + g * 8;
                const uint4 d0 = *(const uint4*)&x_cp[base];
                const uint4 d1 = *(const uint4*)&x_cp[base + 4];
                uint4 fb;
                fb.x = __builtin_amdgcn_perm(d0.y, d0.x, psel);
                fb.y = __builtin_amdgcn_perm(d0.w, d0.z, psel);
                fb.z = __builtin_amdgcn_perm(d1.y, d1.x, psel);
                fb.w = __builtin_amdgcn_perm(d1.w, d1.z, psel);
                const bf16x8 bfr = u4_frag(fb);
                acc2[0][ct] = __builtin_amdgcn_mfma_f32_16x16x32_bf16(afr[0], bfr, acc2[0][ct], 0, 0, 0);
                acc2[1][ct] = __builtin_amdgcn_mfma_f32_16x16x32_bf16(afr[1], bfr, acc2[1][ct], 0, 0, 0);
            }
        }
    }

    // ---- block awsum[k] ----
    #pragma unroll
    for (int i = 0; i < 8; ++i) {
        float v = awacc[i];
        v += __shfl_xor(v, 1);
        v += __shfl_xor(v, 2);
        v += __shfl_xor(v, 4);
        v += __shfl_xor(v, 8);
        awacc[i] = v;
    }
    if (nloc == 0) {
        #pragma unroll
        for (int i = 0; i < 8; ++i) {
            const int k = 16 * (i >> 2) + 4 * g + (i & 3);
            atomicAdd(&awsum[k], awacc[i]);
        }
    }
    __syncthreads();

    // ---- epilogue: fold -awsum*cw (fp32), atomicAdd partials ----
    float* ob = out + (size_t)b * Kc * Cc;
    #pragma unroll
    for (int t = 0; t < 2; ++t)
        #pragma unroll
        for (int ct = 0; ct < 8; ++ct)
            #pragma unroll
            for (int r = 0; r < 4; ++r) {
                const int k = 16 * t + 4 * g + r;
                const int c = 128 * wv + 16 * ct + nloc;
                const float val = fmaf(-awsum[k], cw[k * Cc + c], acc2[t][ct][r]);
                atomicAdd(&ob[k * Cc + c], val);
            }
}

extern "C" void kernel_launch(void* const* d_in, const int* in_sizes, int n_in,
                              void* d_out, int out_size, void* d_ws, size_t ws_size,
                              hipStream_t stream) {
    const float* x     = (const float*)d_in[0];
    const float* cwp   = (const float*)d_in[1];
    const float* scale = (const float*)d_in[2];
    float* out = (float*)d_out;

    unsigned short* cwb = (unsigned short*)d_ws;                       // 32 KB
    float*          c2  = (float*)((char*)d_ws + Kc * Cc * sizeof(unsigned short));

    hipMemsetAsync(out, 0, (size_t)out_size * sizeof(float), stream);
    enc_prep<<<dim3(Kc), dim3(256), 0, stream>>>(cwp, cwb, c2);
    enc_mfma2<<<dim3(512), dim3(256), 0, stream>>>(x, cwp, scale, cwb, c2, out);
}

// Round 4
// 438.972 us; speedup vs baseline: 1.0282x; 1.0282x over previous
//
#include <hip/hip_runtime.h>
#include <hip/hip_bf16.h>

// Encoding (deep-TEN) fused MFMA kernel for MI355X (gfx950), round 4.
// x:(B,C,H,W) fp32, codewords:(K,C) fp32, scale:(K) -> enc:(B,K,C) fp32
//
// Round-4 change: epilogue atomics (8.4M device-scope fp32 atomicAdd,
// ~32-way colliding, measured write-through to HBM) replaced by per-block
// partial stores into d_ws + a reduce kernel. Staging pack now uses
// v_cvt_pk_bf16_f32 via __float22bfloat162_rn.
//
// prep: cw fp32 -> bf16 in d_ws (+ c2[k]).
// main: per block (b,grp): 4-5 tiles of 64 positions.
//   staging: float4-coalesced x loads, c-pair pack, ds_write_b128.
//   matmul1 XC^T[k][n]: B-frags from x_cp LDS, A-frags from global bf16 cw.
//   softmax over K=32 in registers (MFMA C-layout + xor-shfl 16/32).
//   matmul2 ENC[k][c]: A from aw_lds, B from x_cp (b128 + v_perm parity),
//     64 persistent fp32 acc/lane.
//   epilogue: block awsum, fold -awsum*cw, plain stores to ws partials.
// reduce: out[b][k][c] = sum over 32 grp partials (float4, coalesced).

typedef float  f32x4  __attribute__((ext_vector_type(4)));
typedef short  bf16x8 __attribute__((ext_vector_type(8)));

namespace {
constexpr int Cc   = 512;
constexpr int Nc   = 9216;   // 96*96
constexpr int Kc   = 32;
constexpr int XROW = 68;     // u32 per c-pair row (272 B)
constexpr int SAH  = 72;     // aw_lds halfwords per row (144 B)
constexpr size_t PART_OFF = 65536;   // partials offset in d_ws (bytes)
}

static __device__ inline unsigned short f2bf(float f) {
    unsigned int u = __float_as_uint(f);
    u += 0x7fffu + ((u >> 16) & 1u);      // RNE (finite inputs)
    return (unsigned short)(u >> 16);
}
static __device__ inline unsigned int pack_bf16(float a, float b) {
    union { __hip_bfloat162 h; unsigned int u; } cv;
    cv.h = __float22bfloat162_rn(make_float2(a, b));   // v_cvt_pk_bf16_f32
    return cv.u;
}
static __device__ inline bf16x8 u4_frag(uint4 d) {
    union { uint4 u; bf16x8 v; } cv; cv.u = d; return cv.v;
}

// ---- prep: cw -> bf16 in ws, c2[k] ----
__global__ void enc_prep(const float* __restrict__ cw,
                         unsigned short* __restrict__ cwb,
                         float* __restrict__ c2)
{
    const int k = blockIdx.x;           // 32 blocks
    const int t = threadIdx.x;          // 256 threads
    float s = 0.f;
    #pragma unroll
    for (int h = 0; h < 2; ++h) {
        const int c = t + 256 * h;
        const float v = cw[k * Cc + c];
        cwb[k * Cc + c] = f2bf(v);
        s = fmaf(v, v, s);
    }
    s += __shfl_xor(s, 1);  s += __shfl_xor(s, 2);  s += __shfl_xor(s, 4);
    s += __shfl_xor(s, 8);  s += __shfl_xor(s, 16); s += __shfl_xor(s, 32);
    __shared__ float ps[4];
    if ((t & 63) == 0) ps[t >> 6] = s;
    __syncthreads();
    if (t == 0) c2[k] = ps[0] + ps[1] + ps[2] + ps[3];
}

__launch_bounds__(256, 2)
__global__ void enc_mfma2(const float* __restrict__ x,
                          const float* __restrict__ cw,
                          const float* __restrict__ scale,
                          const unsigned short* __restrict__ cwb,
                          const float* __restrict__ c2g,
                          float* __restrict__ part)
{
    __shared__ __attribute__((aligned(16))) unsigned int   x_cp[256 * XROW];  // 69632 B
    __shared__ __attribute__((aligned(16))) unsigned short aw_lds[Kc * SAH];  //  4608 B
    __shared__ __attribute__((aligned(16))) float x2p[4][64];                 //  1024 B
    __shared__ float sc_lds[Kc], c2_lds[Kc], awsum[Kc];

    const int tid  = threadIdx.x;
    const int wv   = tid >> 6;          // wave 0..3
    const int nloc = tid & 15;
    const int g    = (tid >> 4) & 3;
    const int i_q  = tid & 15;          // staging n-quad
    const int cp0  = tid >> 4;          // staging base c-pair 0..15

    const int b   = blockIdx.x >> 5;
    const int grp = blockIdx.x & 31;
    const int tstart = (grp < 16) ? grp * 5 : 80 + (grp - 16) * 4;
    const int tcnt   = (grp < 16) ? 5 : 4;
    const float* __restrict__ xb = x + (size_t)b * Cc * Nc;

    if (tid < Kc) { sc_lds[tid] = scale[tid]; c2_lds[tid] = c2g[tid]; awsum[tid] = 0.f; }
    __syncthreads();

    // per-lane k constants (MFMA C-layout rows: k = 16t + 4g + r)
    float sc8[8], c28[8];
    #pragma unroll
    for (int i = 0; i < 8; ++i) {
        const int k = 16 * (i >> 2) + 4 * g + (i & 3);
        sc8[i] = sc_lds[k];
        c28[i] = c2_lds[k];
    }

    f32x4 acc2[2][8];
    #pragma unroll
    for (int t = 0; t < 2; ++t)
        #pragma unroll
        for (int ct = 0; ct < 8; ++ct) acc2[t][ct] = (f32x4)0.f;
    float awacc[8] = {0.f,0.f,0.f,0.f,0.f,0.f,0.f,0.f};

    const unsigned psel = (nloc & 1) ? 0x07060302u : 0x05040100u;

    for (int tt = 0; tt < tcnt; ++tt) {
        const int n0 = (tstart + tt) * 64;
        __syncthreads();   // prev matmul2 x_cp/aw reads + prev softmax x2p reads done

        // ---- staging: 16 cells of (c-pair, n-quad); float4 loads, b128 writes ----
        float x2q[4] = {0.f, 0.f, 0.f, 0.f};
        #pragma unroll 8
        for (int j = 0; j < 16; ++j) {
            const int cp = cp0 + 16 * j;
            const float* pa = xb + (size_t)(2 * cp) * Nc + n0 + 4 * i_q;
            const float4 va = *(const float4*)pa;
            const float4 vb = *(const float4*)(pa + Nc);
            x2q[0] = fmaf(va.x, va.x, fmaf(vb.x, vb.x, x2q[0]));
            x2q[1] = fmaf(va.y, va.y, fmaf(vb.y, vb.y, x2q[1]));
            x2q[2] = fmaf(va.z, va.z, fmaf(vb.z, vb.z, x2q[2]));
            x2q[3] = fmaf(va.w, va.w, fmaf(vb.w, vb.w, x2q[3]));
            uint4 pk;
            pk.x = pack_bf16(va.x, vb.x);
            pk.y = pack_bf16(va.y, vb.y);
            pk.z = pack_bf16(va.z, vb.z);
            pk.w = pack_bf16(va.w, vb.w);
            *(uint4*)&x_cp[cp * XROW + 4 * i_q] = pk;
        }
        // x2 wave partials (over this wave's channel subset) -> x2p[wv][n]
        #pragma unroll
        for (int r = 0; r < 4; ++r) {
            x2q[r] += __shfl_xor(x2q[r], 16);
            x2q[r] += __shfl_xor(x2q[r], 32);
        }
        if ((tid & 63) < 16)
            *(float4*)&x2p[wv][4 * i_q] = make_float4(x2q[0], x2q[1], x2q[2], x2q[3]);
        __syncthreads();

        // ---- matmul1: XC^T[k][n], B from x_cp LDS, A from global bf16 cw ----
        f32x4 acc1[2];
        acc1[0] = (f32x4)0.f; acc1[1] = (f32x4)0.f;
        #pragma unroll 4
        for (int cs = 0; cs < 16; ++cs) {
            const int rb = (cs * 16 + g * 4) * XROW + 16 * wv + nloc;
            uint4 bf;
            bf.x = x_cp[rb];
            bf.y = x_cp[rb + XROW];
            bf.z = x_cp[rb + 2 * XROW];
            bf.w = x_cp[rb + 3 * XROW];
            const bf16x8 bfr = u4_frag(bf);
            #pragma unroll
            for (int t = 0; t < 2; ++t) {
                const uint4 af = *(const uint4*)&cwb[(16 * t + nloc) * Cc + cs * 32 + g * 8];
                acc1[t] = __builtin_amdgcn_mfma_f32_16x16x32_bf16(u4_frag(af), bfr, acc1[t], 0, 0, 0);
            }
        }

        // ---- softmax over K=32 in registers; n = 16*wv + nloc ----
        const int ncol = 16 * wv + nloc;
        const float x2 = x2p[0][ncol] + x2p[1][ncol] + x2p[2][ncol] + x2p[3][ncol];
        float l[8], aw[8];
        float m = -1e30f;
        #pragma unroll
        for (int i = 0; i < 8; ++i) {
            const float xc = acc1[i >> 2][i & 3];
            l[i] = sc8[i] * (x2 - 2.f * xc + c28[i]);
            m = fmaxf(m, l[i]);
        }
        m = fmaxf(m, __shfl_xor(m, 16));
        m = fmaxf(m, __shfl_xor(m, 32));
        float s = 0.f;
        #pragma unroll
        for (int i = 0; i < 8; ++i) { aw[i] = __expf(l[i] - m); s += aw[i]; }
        s += __shfl_xor(s, 16);
        s += __shfl_xor(s, 32);
        const float inv = 1.f / s;
        #pragma unroll
        for (int i = 0; i < 8; ++i) {
            aw[i] *= inv;
            awacc[i] += aw[i];
            const int k = 16 * (i >> 2) + 4 * g + (i & 3);
            aw_lds[k * SAH + ncol] = f2bf(aw[i]);
        }
        __syncthreads();

        // ---- matmul2: ENC[k][c] += AW^T · X^T over 64 n ----
        #pragma unroll
        for (int ns = 0; ns < 2; ++ns) {
            bf16x8 afr[2];
            #pragma unroll
            for (int t = 0; t < 2; ++t)
                afr[t] = u4_frag(*(const uint4*)&aw_lds[(16 * t + nloc) * SAH + ns * 32 + g * 8]);
            #pragma unroll
            for (int ct = 0; ct < 8; ++ct) {
                const int base = (64 * wv + 8 * ct + (nloc >> 1)) * XROW + ns * 32 + g * 8;
                const uint4 d0 = *(const uint4*)&x_cp[base];
                const uint4 d1 = *(const uint4*)&x_cp[base + 4];
                uint4 fb;
                fb.x = __builtin_amdgcn_perm(d0.y, d0.x, psel);
                fb.y = __builtin_amdgcn_perm(d0.w, d0.z, psel);
                fb.z = __builtin_amdgcn_perm(d1.y, d1.x, psel);
                fb.w = __builtin_amdgcn_perm(d1.w, d1.z, psel);
                const bf16x8 bfr = u4_frag(fb);
                acc2[0][ct] = __builtin_amdgcn_mfma_f32_16x16x32_bf16(afr[0], bfr, acc2[0][ct], 0, 0, 0);
                acc2[1][ct] = __builtin_amdgcn_mfma_f32_16x16x32_bf16(afr[1], bfr, acc2[1][ct], 0, 0, 0);
            }
        }
    }

    // ---- block awsum[k] ----
    #pragma unroll
    for (int i = 0; i < 8; ++i) {
        float v = awacc[i];
        v += __shfl_xor(v, 1);
        v += __shfl_xor(v, 2);
        v += __shfl_xor(v, 4);
        v += __shfl_xor(v, 8);
        awacc[i] = v;
    }
    if (nloc == 0) {
        #pragma unroll
        for (int i = 0; i < 8; ++i) {
            const int k = 16 * (i >> 2) + 4 * g + (i & 3);
            atomicAdd(&awsum[k], awacc[i]);
        }
    }
    __syncthreads();

    // ---- epilogue: fold -awsum*cw (fp32), plain stores to ws partials ----
    float* pb = part + (size_t)blockIdx.x * (Kc * Cc);
    #pragma unroll
    for (int t = 0; t < 2; ++t)
        #pragma unroll
        for (int ct = 0; ct < 8; ++ct)
            #pragma unroll
            for (int r = 0; r < 4; ++r) {
                const int k = 16 * t + 4 * g + r;
                const int c = 128 * wv + 16 * ct + nloc;
                pb[k * Cc + c] = fmaf(-awsum[k], cw[k * Cc + c], acc2[t][ct][r]);
            }
}

// ---- reduce: out[b][k][c] = sum_{grp<32} part[(b*32+grp)][k][c] ----
__global__ void enc_reduce(const float* __restrict__ part,
                           float* __restrict__ out)
{
    const int idx = blockIdx.x * 256 + threadIdx.x;   // one float4, 0..65535
    const int c4  = idx & 127;                        // 128 float4 per (b,k)
    const int bk  = idx >> 7;                         // b*32 + k
    const int b   = bk >> 5;
    const int k   = bk & 31;
    const float4* p = (const float4*)part + ((size_t)b * 32) * (Kc * Cc / 4) + k * (Cc / 4) + c4;
    float4 s = make_float4(0.f, 0.f, 0.f, 0.f);
    #pragma unroll 8
    for (int g = 0; g < 32; ++g) {
        const float4 v = p[(size_t)g * (Kc * Cc / 4)];
        s.x += v.x; s.y += v.y; s.z += v.z; s.w += v.w;
    }
    ((float4*)out)[idx] = s;
}

extern "C" void kernel_launch(void* const* d_in, const int* in_sizes, int n_in,
                              void* d_out, int out_size, void* d_ws, size_t ws_size,
                              hipStream_t stream) {
    const float* x     = (const float*)d_in[0];
    const float* cwp   = (const float*)d_in[1];
    const float* scale = (const float*)d_in[2];
    float* out = (float*)d_out;

    unsigned short* cwb  = (unsigned short*)d_ws;                         // 32 KB
    float*          c2   = (float*)((char*)d_ws + Kc * Cc * sizeof(unsigned short));
    float*          part = (float*)((char*)d_ws + PART_OFF);              // 32 MB

    enc_prep<<<dim3(Kc), dim3(256), 0, stream>>>(cwp, cwb, c2);
    enc_mfma2<<<dim3(512), dim3(256), 0, stream>>>(x, cwp, scale, cwb, c2, part);
    enc_reduce<<<dim3(256), dim3(256), 0, stream>>>(part, out);
}